// Round 9
// baseline (1493.605 us; speedup 1.0000x reference)
//
#include <hip/hip_runtime.h>
#include <hip/hip_bf16.h>
#include <math.h>

#define NN 100000
#define NE 400000
#define NG 2048
#define BN_EPS 1e-5f
#define NB_SCAN 98   // ceil(NN/1024)

typedef short short8 __attribute__((ext_vector_type(8)));
typedef float f32x4 __attribute__((ext_vector_type(4)));

__device__ __forceinline__ float bf2f(unsigned short u){
  union { unsigned u; float f; } x; x.u = ((unsigned)u) << 16; return x.f;
}
__device__ __forceinline__ unsigned short f2bf(float f){
  union { float f; unsigned u; } x; x.f = f;
  unsigned r = x.u + 0x7FFFu + ((x.u >> 16) & 1u);
  return (unsigned short)(r >> 16);
}

__global__ void k_zero(float* p, long n){
  long i = (long)blockIdx.x * blockDim.x + threadIdx.x;
  if (i < n) p[i] = 0.f;
}

__global__ void k_initcoef(float* coefA, float* coefB){
  coefA[threadIdx.x] = 1.f;
  coefB[threadIdx.x] = 0.f;
}

__global__ void k_deg(const int* __restrict__ dst, int* __restrict__ deg){
  int e = blockIdx.x * blockDim.x + threadIdx.x;
  if (e < NE) atomicAdd(&deg[dst[e]], 1);
}

__global__ void k_dinv(const int* __restrict__ deg, float* __restrict__ dinv){
  int v = blockIdx.x * blockDim.x + threadIdx.x;
  if (v < NN) dinv[v] = rsqrtf((float)(deg[v] + 1));  // +1 = self loop
}

// ---- parallel exclusive scan of deg -> rowptr/cursor (3 phases) ----
__global__ void k_scan1(const int* __restrict__ deg, int* __restrict__ bsum){
  __shared__ int s[256];
  int b = blockIdx.x, t = threadIdx.x;
  int base = b * 1024;
  int v = 0;
  #pragma unroll
  for (int i = 0; i < 4; ++i){
    int idx = base + t + i * 256;
    if (idx < NN) v += deg[idx];
  }
  s[t] = v; __syncthreads();
  for (int o = 128; o; o >>= 1){
    if (t < o) s[t] += s[t + o];
    __syncthreads();
  }
  if (t == 0) bsum[b] = s[0];
}

__global__ void k_scan2(const int* __restrict__ bsum, int* __restrict__ boff){
  __shared__ int s[128];
  int t = threadIdx.x;
  int v = (t < NB_SCAN) ? bsum[t] : 0;
  s[t] = v; __syncthreads();
  for (int o = 1; o < 128; o <<= 1){
    int x = (t >= o) ? s[t - o] : 0;
    __syncthreads();
    s[t] += x;
    __syncthreads();
  }
  if (t < NB_SCAN) boff[t] = s[t] - v;  // exclusive block offsets
}

__global__ void k_scan3(const int* __restrict__ deg, const int* __restrict__ boff,
                        int* __restrict__ rowptr, int* __restrict__ cursor){
  __shared__ int s[256];
  int b = blockIdx.x, t = threadIdx.x;
  int base = b * 1024 + t * 4;
  int d[4]; int loc = 0;
  #pragma unroll
  for (int i = 0; i < 4; ++i){
    int idx = base + i;
    d[i] = (idx < NN) ? deg[idx] : 0;
    loc += d[i];
  }
  s[t] = loc; __syncthreads();
  for (int o = 1; o < 256; o <<= 1){
    int x = (t >= o) ? s[t - o] : 0;
    __syncthreads();
    s[t] += x;
    __syncthreads();
  }
  int run = boff[b] + s[t] - loc;
  #pragma unroll
  for (int i = 0; i < 4; ++i){
    int idx = base + i;
    if (idx < NN){ rowptr[idx] = run; cursor[idx] = run; run += d[i]; }
  }
  if (b == NB_SCAN - 1 && t == 255) rowptr[NN] = run;  // = NE
}

// CSR fill: bucket edges by dst; store src index and weight dinv[src]
__global__ void k_fill(const int* __restrict__ src, const int* __restrict__ dst,
                       const float* __restrict__ dinv, int* __restrict__ cursor,
                       int* __restrict__ csr_src, float* __restrict__ csr_w){
  int e = blockIdx.x * blockDim.x + threadIdx.x;
  if (e >= NE) return;
  int s = src[e], d = dst[e];
  int p = atomicAdd(&cursor[d], 1);
  csr_src[p] = s;
  csr_w[p] = dinv[s];
}

// graph boundaries from sorted batch ids; start[NG] = NN
__global__ void k_bounds(const int* __restrict__ batch, int* __restrict__ start){
  int i = blockIdx.x * blockDim.x + threadIdx.x;
  if (i >= NN) return;
  int cur = batch[i];
  int prev = (i == 0) ? -1 : batch[i - 1];
  for (int g = prev + 1; g <= cur; ++g) start[g] = i;
  if (i == NN - 1) for (int g = cur + 1; g <= NG; ++g) start[g] = NN;
}

// Repack W[K,256] f32 -> bf16 MFMA B-operand order
__global__ void k_repack(const float* __restrict__ W,
                         unsigned short* __restrict__ Wp, int K){
  int gid = blockIdx.x * blockDim.x + threadIdx.x;
  int total = (K >> 5) * 16 * 64;
  if (gid >= total) return;
  int l = gid & 63;
  int t = (gid >> 6) & 15;
  int kb = gid >> 10;
  int q = l >> 4, m = l & 15;
  unsigned short* o = Wp + (size_t)gid * 8;
  #pragma unroll
  for (int j = 0; j < 8; ++j)
    o[j] = f2bf(W[(size_t)(kb * 32 + q * 8 + j) * 256 + t * 16 + m]);
}

// B[N,256] = (cA[k]*A[N,K]+cB[k]) @ Wp  — BN of previous layer folded into A-load.
__global__ __launch_bounds__(256) void k_gemm(const float* __restrict__ A,
                                              const unsigned short* __restrict__ Wp,
                                              const float* __restrict__ cA,
                                              const float* __restrict__ cB,
                                              float* __restrict__ out, int K){
  __shared__ float sA[256], sB[256];
  if (threadIdx.x < K){
    sA[threadIdx.x] = cA[threadIdx.x];
    sB[threadIdx.x] = cB[threadIdx.x];
  }
  __syncthreads();
  int lane = threadIdx.x & 63;
  int wave = threadIdx.x >> 6;
  int m0 = blockIdx.x * 64 + wave * 16;
  int q = lane >> 4, m = lane & 15;
  int arow = m0 + m;
  bool valid = arow < NN;
  const float* ap = A + (size_t)arow * K + q * 8;
  f32x4 acc[16] = {};
  int nkb = K >> 5;
  for (int kb = 0; kb < nkb; ++kb){
    short8 ahi = {}, alo = {};
    if (valid){
      f32x4 x0 = *(const f32x4*)(ap + kb * 32);
      f32x4 x1 = *(const f32x4*)(ap + kb * 32 + 4);
      float xs[8] = {x0[0], x0[1], x0[2], x0[3], x1[0], x1[1], x1[2], x1[3]};
      int kk = kb * 32 + q * 8;
      #pragma unroll
      for (int j = 0; j < 8; ++j){
        float xv = sA[kk + j] * xs[j] + sB[kk + j];
        unsigned short h = f2bf(xv);
        ahi[j] = (short)h;
        alo[j] = (short)f2bf(xv - bf2f(h));
      }
    }
    const unsigned short* wp = Wp + ((size_t)kb * 1024 + lane) * 8;
    #pragma unroll
    for (int t = 0; t < 16; ++t){
      short8 b = *(const short8*)(wp + (size_t)t * 512);
      acc[t] = __builtin_amdgcn_mfma_f32_16x16x32_bf16(ahi, b, acc[t], 0, 0, 0);
      acc[t] = __builtin_amdgcn_mfma_f32_16x16x32_bf16(alo, b, acc[t], 0, 0, 0);
    }
  }
  int r0 = m0 + q * 4;
  #pragma unroll
  for (int t = 0; t < 16; ++t)
    #pragma unroll
    for (int r = 0; r < 4; ++r){
      int row = r0 + r;
      if (row < NN) out[(size_t)row * 256 + t * 16 + m] = acc[t][r];
    }
}

// Pull aggregation + bias + tanh + BN-stats, fused. C holds PRE-BN tanh output.
// grid = 2048 blocks (8 blocks/CU -> 100% wave occupancy) for latency hiding.
__global__ __launch_bounds__(256) void k_gather(const int* __restrict__ rowptr,
                                                const int* __restrict__ csr_src,
                                                const float* __restrict__ csr_w,
                                                const float* __restrict__ dinv,
                                                const float* __restrict__ B,
                                                const float* __restrict__ bias,
                                                float* __restrict__ C,
                                                float* __restrict__ gsum,
                                                float* __restrict__ gsumsq){
  __shared__ float lsum[4][256];
  __shared__ float lss[4][256];
  int lane = threadIdx.x & 63;
  int wv = threadIdx.x >> 6;
  int gwv = (int)((blockIdx.x * 256 + threadIdx.x) >> 6);
  int nwv = (int)((gridDim.x * 256) >> 6);
  int c4 = lane * 4;
  f32x4 bia = *(const f32x4*)(bias + c4);
  f32x4 s = {}, ss = {};
  for (int v = gwv; v < NN; v += nwv){
    float dv = dinv[v];
    f32x4 acc = dv * (*(const f32x4*)(B + (size_t)v * 256 + c4));
    int e1 = rowptr[v + 1];
    for (int e = rowptr[v]; e < e1; ++e){
      int sv = csr_src[e];
      float w = csr_w[e];
      acc += w * (*(const f32x4*)(B + (size_t)sv * 256 + c4));
    }
    f32x4 t;
    t[0] = tanhf(dv * acc[0] + bia[0]);
    t[1] = tanhf(dv * acc[1] + bia[1]);
    t[2] = tanhf(dv * acc[2] + bia[2]);
    t[3] = tanhf(dv * acc[3] + bia[3]);
    *(f32x4*)(C + (size_t)v * 256 + c4) = t;
    s += t;
    ss += t * t;
  }
  *(f32x4*)(&lsum[wv][c4]) = s;
  *(f32x4*)(&lss[wv][c4]) = ss;
  __syncthreads();
  if (wv == 0){
    f32x4 a = *(f32x4*)(&lsum[0][c4]);
    f32x4 b = *(f32x4*)(&lss[0][c4]);
    #pragma unroll
    for (int w2 = 1; w2 < 4; ++w2){
      a += *(f32x4*)(&lsum[w2][c4]);
      b += *(f32x4*)(&lss[w2][c4]);
    }
    #pragma unroll
    for (int i = 0; i < 4; ++i){
      atomicAdd(&gsum[c4 + i], a[i]);
      atomicAdd(&gsumsq[c4 + i], b[i]);
    }
  }
}

__global__ void k_bncoef(const float* __restrict__ gsum, const float* __restrict__ gsumsq,
                         const float* __restrict__ gamma,
                         const float* __restrict__ beta,
                         float* __restrict__ coefA, float* __restrict__ coefB){
  int c = threadIdx.x;
  float mu = gsum[c] * (1.f / NN);
  float var = gsumsq[c] * (1.f / NN) - mu * mu;
  float a = gamma[c] / sqrtf(var + BN_EPS);
  coefA[c] = a;
  coefB[c] = beta[c] - mu * a;
}

// block per graph; thread c: max&min over pre-BN C, then apply affine
__global__ void k_pool(const float* __restrict__ C, const int* __restrict__ start,
                       const float* __restrict__ coefA, const float* __restrict__ coefB,
                       float* __restrict__ out){
  int g = blockIdx.x, c = threadIdx.x;
  int s = start[g], e = start[g + 1];
  float mx = -INFINITY, mn = INFINITY;
  for (int row = s; row < e; ++row){
    float v = C[(size_t)row * 256 + c];
    mx = fmaxf(mx, v);
    mn = fminf(mn, v);
  }
  float a = coefA[c], b = coefB[c];
  float r = (a >= 0.f) ? (a * mx + b) : (a * mn + b);
  out[(size_t)g * 256 + c] = (e > s) ? r : 0.f;
}

extern "C" void kernel_launch(void* const* d_in, const int* in_sizes, int n_in,
                              void* d_out, int out_size, void* d_ws, size_t ws_size,
                              hipStream_t stream){
  const float* x = (const float*)d_in[0];
  const int* eidx = (const int*)d_in[1];
  const int* batch = (const int*)d_in[2];
  const int* src  = eidx;
  const int* dstv = eidx + NE;
  const float* W[3]  = {(const float*)d_in[3],  (const float*)d_in[7],  (const float*)d_in[11]};
  const float* bb[3] = {(const float*)d_in[4],  (const float*)d_in[8],  (const float*)d_in[12]};
  const float* gm[3] = {(const float*)d_in[5],  (const float*)d_in[9],  (const float*)d_in[13]};
  const float* bt[3] = {(const float*)d_in[6],  (const float*)d_in[10], (const float*)d_in[14]};
  float* out = (float*)d_out;

  char* w = (char*)d_ws;
  float* B = (float*)w;            w += (size_t)NN * 256 * 4;   // 102.4 MB
  float* C = (float*)w;            w += (size_t)NN * 256 * 4;   // 102.4 MB
  float* dinv = (float*)w;         w += (size_t)NN * 4;
  int* deg = (int*)w;              w += (size_t)NN * 4;
  int* rowptr = (int*)w;           w += (size_t)(NN + 1) * 4;
  int* cursor = (int*)w;           w += (size_t)NN * 4;
  int* csr_src = (int*)w;          w += (size_t)NE * 4;
  float* csr_w = (float*)w;        w += (size_t)NE * 4;
  int* bsum = (int*)w;             w += (size_t)NB_SCAN * 4;
  int* boff = (int*)w;             w += (size_t)NB_SCAN * 4;
  unsigned short* Wp = (unsigned short*)w; w += (size_t)256 * 256 * 2;
  float* gsum = (float*)w;         w += 256 * 4;
  float* gsumsq = (float*)w;       w += 256 * 4;
  float* coefA = (float*)w;        w += 256 * 4;
  float* coefB = (float*)w;        w += 256 * 4;
  int* start = (int*)w;            w += (size_t)(NG + 1) * 4;

  // graph prep (once per call)
  k_zero<<<(NN + 255) / 256, 256, 0, stream>>>((float*)deg, NN);
  k_deg<<<(NE + 255) / 256, 256, 0, stream>>>(dstv, deg);
  k_dinv<<<(NN + 255) / 256, 256, 0, stream>>>(deg, dinv);
  k_scan1<<<NB_SCAN, 256, 0, stream>>>(deg, bsum);
  k_scan2<<<1, 128, 0, stream>>>(bsum, boff);
  k_scan3<<<NB_SCAN, 256, 0, stream>>>(deg, boff, rowptr, cursor);
  k_fill<<<(NE + 255) / 256, 256, 0, stream>>>(src, dstv, dinv, cursor, csr_src, csr_w);
  k_bounds<<<(NN + 255) / 256, 256, 0, stream>>>(batch, start);
  k_initcoef<<<1, 256, 0, stream>>>(coefA, coefB);   // identity for layer 0 GEMM

  const float* Ain = x;
  int K = 128;
  for (int L = 0; L < 3; ++L){
    int nrep = (K >> 5) * 16 * 64;
    k_repack<<<(nrep + 255) / 256, 256, 0, stream>>>(W[L], Wp, K);
    k_gemm<<<(NN + 63) / 64, 256, 0, stream>>>(Ain, Wp, coefA, coefB, B, K);
    k_zero<<<2, 256, 0, stream>>>(gsum, 512);  // gsum+gsumsq contiguous
    k_gather<<<2048, 256, 0, stream>>>(rowptr, csr_src, csr_w, dinv, B, bb[L], C, gsum, gsumsq);
    k_bncoef<<<1, 256, 0, stream>>>(gsum, gsumsq, gm[L], bt[L], coefA, coefB);
    k_pool<<<NG, 256, 0, stream>>>(C, start, coefA, coefB, out + (size_t)L * NG * 256);
    Ain = C; K = 256;
  }
}

// Round 10
// 1161.500 us; speedup vs baseline: 1.2859x; 1.2859x over previous
//
#include <hip/hip_runtime.h>
#include <hip/hip_bf16.h>
#include <math.h>

#define NN 100000
#define NE 400000
#define NG 2048
#define BN_EPS 1e-5f
#define NB_SCAN 98   // ceil(NN/1024)

typedef short short8 __attribute__((ext_vector_type(8)));
typedef float f32x4 __attribute__((ext_vector_type(4)));
typedef unsigned short u16x4 __attribute__((ext_vector_type(4)));

__device__ __forceinline__ float bf2f(unsigned short u){
  union { unsigned u; float f; } x; x.u = ((unsigned)u) << 16; return x.f;
}
__device__ __forceinline__ unsigned short f2bf(float f){
  union { float f; unsigned u; } x; x.f = f;
  unsigned r = x.u + 0x7FFFu + ((x.u >> 16) & 1u);
  return (unsigned short)(r >> 16);
}

__global__ void k_zero(float* p, long n){
  long i = (long)blockIdx.x * blockDim.x + threadIdx.x;
  if (i < n) p[i] = 0.f;
}

__global__ void k_initcoef(float* coefA, float* coefB){
  coefA[threadIdx.x] = 1.f;
  coefB[threadIdx.x] = 0.f;
}

__global__ void k_deg(const int* __restrict__ dst, int* __restrict__ deg){
  int e = blockIdx.x * blockDim.x + threadIdx.x;
  if (e < NE) atomicAdd(&deg[dst[e]], 1);
}

__global__ void k_dinv(const int* __restrict__ deg, float* __restrict__ dinv){
  int v = blockIdx.x * blockDim.x + threadIdx.x;
  if (v < NN) dinv[v] = rsqrtf((float)(deg[v] + 1));  // +1 = self loop
}

// ---- parallel exclusive scan of deg -> rowptr/cursor (3 phases) ----
__global__ void k_scan1(const int* __restrict__ deg, int* __restrict__ bsum){
  __shared__ int s[256];
  int b = blockIdx.x, t = threadIdx.x;
  int base = b * 1024;
  int v = 0;
  #pragma unroll
  for (int i = 0; i < 4; ++i){
    int idx = base + t + i * 256;
    if (idx < NN) v += deg[idx];
  }
  s[t] = v; __syncthreads();
  for (int o = 128; o; o >>= 1){
    if (t < o) s[t] += s[t + o];
    __syncthreads();
  }
  if (t == 0) bsum[b] = s[0];
}

__global__ void k_scan2(const int* __restrict__ bsum, int* __restrict__ boff){
  __shared__ int s[128];
  int t = threadIdx.x;
  int v = (t < NB_SCAN) ? bsum[t] : 0;
  s[t] = v; __syncthreads();
  for (int o = 1; o < 128; o <<= 1){
    int x = (t >= o) ? s[t - o] : 0;
    __syncthreads();
    s[t] += x;
    __syncthreads();
  }
  if (t < NB_SCAN) boff[t] = s[t] - v;  // exclusive block offsets
}

__global__ void k_scan3(const int* __restrict__ deg, const int* __restrict__ boff,
                        int* __restrict__ rowptr, int* __restrict__ cursor){
  __shared__ int s[256];
  int b = blockIdx.x, t = threadIdx.x;
  int base = b * 1024 + t * 4;
  int d[4]; int loc = 0;
  #pragma unroll
  for (int i = 0; i < 4; ++i){
    int idx = base + i;
    d[i] = (idx < NN) ? deg[idx] : 0;
    loc += d[i];
  }
  s[t] = loc; __syncthreads();
  for (int o = 1; o < 256; o <<= 1){
    int x = (t >= o) ? s[t - o] : 0;
    __syncthreads();
    s[t] += x;
    __syncthreads();
  }
  int run = boff[b] + s[t] - loc;
  #pragma unroll
  for (int i = 0; i < 4; ++i){
    int idx = base + i;
    if (idx < NN){ rowptr[idx] = run; cursor[idx] = run; run += d[i]; }
  }
  if (b == NB_SCAN - 1 && t == 255) rowptr[NN] = run;  // = NE
}

// CSR fill: bucket edges by dst; store src index and weight dinv[src]
__global__ void k_fill(const int* __restrict__ src, const int* __restrict__ dst,
                       const float* __restrict__ dinv, int* __restrict__ cursor,
                       int* __restrict__ csr_src, float* __restrict__ csr_w){
  int e = blockIdx.x * blockDim.x + threadIdx.x;
  if (e >= NE) return;
  int s = src[e], d = dst[e];
  int p = atomicAdd(&cursor[d], 1);
  csr_src[p] = s;
  csr_w[p] = dinv[s];
}

// graph boundaries from sorted batch ids; start[NG] = NN
__global__ void k_bounds(const int* __restrict__ batch, int* __restrict__ start){
  int i = blockIdx.x * blockDim.x + threadIdx.x;
  if (i >= NN) return;
  int cur = batch[i];
  int prev = (i == 0) ? -1 : batch[i - 1];
  for (int g = prev + 1; g <= cur; ++g) start[g] = i;
  if (i == NN - 1) for (int g = cur + 1; g <= NG; ++g) start[g] = NN;
}

// Repack W[K,256] f32 -> bf16 MFMA B-operand order
__global__ void k_repack(const float* __restrict__ W,
                         unsigned short* __restrict__ Wp, int K){
  int gid = blockIdx.x * blockDim.x + threadIdx.x;
  int total = (K >> 5) * 16 * 64;
  if (gid >= total) return;
  int l = gid & 63;
  int t = (gid >> 6) & 15;
  int kb = gid >> 10;
  int q = l >> 4, m = l & 15;
  unsigned short* o = Wp + (size_t)gid * 8;
  #pragma unroll
  for (int j = 0; j < 8; ++j)
    o[j] = f2bf(W[(size_t)(kb * 32 + q * 8 + j) * 256 + t * 16 + m]);
}

// B[N,256](bf16) = (cA[k]*A[N,K]+cB[k]) @ Wp  — BN of prev layer folded in.
__global__ __launch_bounds__(256) void k_gemm(const float* __restrict__ A,
                                              const unsigned short* __restrict__ Wp,
                                              const float* __restrict__ cA,
                                              const float* __restrict__ cB,
                                              unsigned short* __restrict__ out, int K){
  __shared__ float sA[256], sB[256];
  if (threadIdx.x < K){
    sA[threadIdx.x] = cA[threadIdx.x];
    sB[threadIdx.x] = cB[threadIdx.x];
  }
  __syncthreads();
  int lane = threadIdx.x & 63;
  int wave = threadIdx.x >> 6;
  int m0 = blockIdx.x * 64 + wave * 16;
  int q = lane >> 4, m = lane & 15;
  int arow = m0 + m;
  bool valid = arow < NN;
  const float* ap = A + (size_t)arow * K + q * 8;
  f32x4 acc[16] = {};
  int nkb = K >> 5;
  for (int kb = 0; kb < nkb; ++kb){
    short8 ahi = {}, alo = {};
    if (valid){
      f32x4 x0 = *(const f32x4*)(ap + kb * 32);
      f32x4 x1 = *(const f32x4*)(ap + kb * 32 + 4);
      float xs[8] = {x0[0], x0[1], x0[2], x0[3], x1[0], x1[1], x1[2], x1[3]};
      int kk = kb * 32 + q * 8;
      #pragma unroll
      for (int j = 0; j < 8; ++j){
        float xv = sA[kk + j] * xs[j] + sB[kk + j];
        unsigned short h = f2bf(xv);
        ahi[j] = (short)h;
        alo[j] = (short)f2bf(xv - bf2f(h));
      }
    }
    const unsigned short* wp = Wp + ((size_t)kb * 1024 + lane) * 8;
    #pragma unroll
    for (int t = 0; t < 16; ++t){
      short8 b = *(const short8*)(wp + (size_t)t * 512);
      acc[t] = __builtin_amdgcn_mfma_f32_16x16x32_bf16(ahi, b, acc[t], 0, 0, 0);
      acc[t] = __builtin_amdgcn_mfma_f32_16x16x32_bf16(alo, b, acc[t], 0, 0, 0);
    }
  }
  int r0 = m0 + q * 4;
  #pragma unroll
  for (int t = 0; t < 16; ++t)
    #pragma unroll
    for (int r = 0; r < 4; ++r){
      int row = r0 + r;
      if (row < NN) out[(size_t)row * 256 + t * 16 + m] = f2bf(acc[t][r]);
    }
}

// Pull aggregation + bias + tanh + BN-stats, fused; B is bf16 (512B rows).
// grid = 512 blocks — measured optimum (2048 collapsed L2 hit rate, round 9).
__global__ __launch_bounds__(256) void k_gather(const int* __restrict__ rowptr,
                                                const int* __restrict__ csr_src,
                                                const float* __restrict__ csr_w,
                                                const float* __restrict__ dinv,
                                                const unsigned short* __restrict__ B,
                                                const float* __restrict__ bias,
                                                float* __restrict__ C,
                                                float* __restrict__ gsum,
                                                float* __restrict__ gsumsq){
  __shared__ float lsum[4][256];
  __shared__ float lss[4][256];
  int lane = threadIdx.x & 63;
  int wv = threadIdx.x >> 6;
  int gwv = (int)((blockIdx.x * 256 + threadIdx.x) >> 6);
  int nwv = (int)((gridDim.x * 256) >> 6);
  int c4 = lane * 4;
  f32x4 bia = *(const f32x4*)(bias + c4);
  f32x4 s = {}, ss = {};
  for (int v = gwv; v < NN; v += nwv){
    float dv = dinv[v];
    u16x4 bv = *(const u16x4*)(B + (size_t)v * 256 + c4);
    f32x4 acc;
    acc[0] = dv * bf2f(bv[0]);
    acc[1] = dv * bf2f(bv[1]);
    acc[2] = dv * bf2f(bv[2]);
    acc[3] = dv * bf2f(bv[3]);
    int e1 = rowptr[v + 1];
    for (int e = rowptr[v]; e < e1; ++e){
      int sv = csr_src[e];
      float w = csr_w[e];
      u16x4 rv = *(const u16x4*)(B + (size_t)sv * 256 + c4);
      acc[0] += w * bf2f(rv[0]);
      acc[1] += w * bf2f(rv[1]);
      acc[2] += w * bf2f(rv[2]);
      acc[3] += w * bf2f(rv[3]);
    }
    f32x4 t;
    t[0] = tanhf(dv * acc[0] + bia[0]);
    t[1] = tanhf(dv * acc[1] + bia[1]);
    t[2] = tanhf(dv * acc[2] + bia[2]);
    t[3] = tanhf(dv * acc[3] + bia[3]);
    *(f32x4*)(C + (size_t)v * 256 + c4) = t;
    s += t;
    ss += t * t;
  }
  *(f32x4*)(&lsum[wv][c4]) = s;
  *(f32x4*)(&lss[wv][c4]) = ss;
  __syncthreads();
  if (wv == 0){
    f32x4 a = *(f32x4*)(&lsum[0][c4]);
    f32x4 b = *(f32x4*)(&lss[0][c4]);
    #pragma unroll
    for (int w2 = 1; w2 < 4; ++w2){
      a += *(f32x4*)(&lsum[w2][c4]);
      b += *(f32x4*)(&lss[w2][c4]);
    }
    #pragma unroll
    for (int i = 0; i < 4; ++i){
      atomicAdd(&gsum[c4 + i], a[i]);
      atomicAdd(&gsumsq[c4 + i], b[i]);
    }
  }
}

__global__ void k_bncoef(const float* __restrict__ gsum, const float* __restrict__ gsumsq,
                         const float* __restrict__ gamma,
                         const float* __restrict__ beta,
                         float* __restrict__ coefA, float* __restrict__ coefB){
  int c = threadIdx.x;
  float mu = gsum[c] * (1.f / NN);
  float var = gsumsq[c] * (1.f / NN) - mu * mu;
  float a = gamma[c] / sqrtf(var + BN_EPS);
  coefA[c] = a;
  coefB[c] = beta[c] - mu * a;
}

// block per graph; thread c: max&min over pre-BN C, then apply affine
__global__ void k_pool(const float* __restrict__ C, const int* __restrict__ start,
                       const float* __restrict__ coefA, const float* __restrict__ coefB,
                       float* __restrict__ out){
  int g = blockIdx.x, c = threadIdx.x;
  int s = start[g], e = start[g + 1];
  float mx = -INFINITY, mn = INFINITY;
  for (int row = s; row < e; ++row){
    float v = C[(size_t)row * 256 + c];
    mx = fmaxf(mx, v);
    mn = fminf(mn, v);
  }
  float a = coefA[c], b = coefB[c];
  float r = (a >= 0.f) ? (a * mx + b) : (a * mn + b);
  out[(size_t)g * 256 + c] = (e > s) ? r : 0.f;
}

extern "C" void kernel_launch(void* const* d_in, const int* in_sizes, int n_in,
                              void* d_out, int out_size, void* d_ws, size_t ws_size,
                              hipStream_t stream){
  const float* x = (const float*)d_in[0];
  const int* eidx = (const int*)d_in[1];
  const int* batch = (const int*)d_in[2];
  const int* src  = eidx;
  const int* dstv = eidx + NE;
  const float* W[3]  = {(const float*)d_in[3],  (const float*)d_in[7],  (const float*)d_in[11]};
  const float* bb[3] = {(const float*)d_in[4],  (const float*)d_in[8],  (const float*)d_in[12]};
  const float* gm[3] = {(const float*)d_in[5],  (const float*)d_in[9],  (const float*)d_in[13]};
  const float* bt[3] = {(const float*)d_in[6],  (const float*)d_in[10], (const float*)d_in[14]};
  float* out = (float*)d_out;

  char* w = (char*)d_ws;
  unsigned short* B = (unsigned short*)w; w += (size_t)NN * 256 * 2;  // 51.2 MB bf16
  float* C = (float*)w;            w += (size_t)NN * 256 * 4;          // 102.4 MB
  float* dinv = (float*)w;         w += (size_t)NN * 4;
  int* deg = (int*)w;              w += (size_t)NN * 4;
  int* rowptr = (int*)w;           w += (size_t)(NN + 1) * 4;
  int* cursor = (int*)w;           w += (size_t)NN * 4;
  int* csr_src = (int*)w;          w += (size_t)NE * 4;
  float* csr_w = (float*)w;        w += (size_t)NE * 4;
  int* bsum = (int*)w;             w += (size_t)NB_SCAN * 4;
  int* boff = (int*)w;             w += (size_t)NB_SCAN * 4;
  unsigned short* Wp = (unsigned short*)w; w += (size_t)256 * 256 * 2;
  float* gsum = (float*)w;         w += 256 * 4;
  float* gsumsq = (float*)w;       w += 256 * 4;
  float* coefA = (float*)w;        w += 256 * 4;
  float* coefB = (float*)w;        w += 256 * 4;
  int* start = (int*)w;            w += (size_t)(NG + 1) * 4;

  // graph prep (once per call)
  k_zero<<<(NN + 255) / 256, 256, 0, stream>>>((float*)deg, NN);
  k_deg<<<(NE + 255) / 256, 256, 0, stream>>>(dstv, deg);
  k_dinv<<<(NN + 255) / 256, 256, 0, stream>>>(deg, dinv);
  k_scan1<<<NB_SCAN, 256, 0, stream>>>(deg, bsum);
  k_scan2<<<1, 128, 0, stream>>>(bsum, boff);
  k_scan3<<<NB_SCAN, 256, 0, stream>>>(deg, boff, rowptr, cursor);
  k_fill<<<(NE + 255) / 256, 256, 0, stream>>>(src, dstv, dinv, cursor, csr_src, csr_w);
  k_bounds<<<(NN + 255) / 256, 256, 0, stream>>>(batch, start);
  k_initcoef<<<1, 256, 0, stream>>>(coefA, coefB);   // identity for layer 0 GEMM

  const float* Ain = x;
  int K = 128;
  for (int L = 0; L < 3; ++L){
    int nrep = (K >> 5) * 16 * 64;
    k_repack<<<(nrep + 255) / 256, 256, 0, stream>>>(W[L], Wp, K);
    k_gemm<<<(NN + 63) / 64, 256, 0, stream>>>(Ain, Wp, coefA, coefB, B, K);
    k_zero<<<2, 256, 0, stream>>>(gsum, 512);  // gsum+gsumsq contiguous
    k_gather<<<512, 256, 0, stream>>>(rowptr, csr_src, csr_w, dinv, B, bb[L], C, gsum, gsumsq);
    k_bncoef<<<1, 256, 0, stream>>>(gsum, gsumsq, gm[L], bt[L], coefA, coefB);
    k_pool<<<NG, 256, 0, stream>>>(C, start, coefA, coefB, out + (size_t)L * NG * 256);
    Ain = C; K = 256;
  }
}

// Round 11
// 1067.195 us; speedup vs baseline: 1.3996x; 1.0884x over previous
//
#include <hip/hip_runtime.h>
#include <hip/hip_bf16.h>
#include <math.h>

#define NN 100000
#define NE 400000
#define NG 2048
#define BN_EPS 1e-5f
#define NB_SCAN 98   // ceil(NN/1024)

typedef short short8 __attribute__((ext_vector_type(8)));
typedef float f32x4 __attribute__((ext_vector_type(4)));
typedef unsigned short u16x4 __attribute__((ext_vector_type(4)));
typedef unsigned short u16x8 __attribute__((ext_vector_type(8)));

__device__ __forceinline__ float bf2f(unsigned short u){
  union { unsigned u; float f; } x; x.u = ((unsigned)u) << 16; return x.f;
}
__device__ __forceinline__ unsigned short f2bf(float f){
  union { float f; unsigned u; } x; x.f = f;
  unsigned r = x.u + 0x7FFFu + ((x.u >> 16) & 1u);
  return (unsigned short)(r >> 16);
}

__global__ void k_zero(float* p, long n){
  long i = (long)blockIdx.x * blockDim.x + threadIdx.x;
  if (i < n) p[i] = 0.f;
}

__global__ void k_deg(const int* __restrict__ dst, int* __restrict__ deg){
  int e = blockIdx.x * blockDim.x + threadIdx.x;
  if (e < NE) atomicAdd(&deg[dst[e]], 1);
}

__global__ void k_dinv(const int* __restrict__ deg, float* __restrict__ dinv){
  int v = blockIdx.x * blockDim.x + threadIdx.x;
  if (v < NN) dinv[v] = rsqrtf((float)(deg[v] + 1));  // +1 = self loop
}

// ---- parallel exclusive scan of deg -> rowptr/cursor (3 phases) ----
__global__ void k_scan1(const int* __restrict__ deg, int* __restrict__ bsum){
  __shared__ int s[256];
  int b = blockIdx.x, t = threadIdx.x;
  int base = b * 1024;
  int v = 0;
  #pragma unroll
  for (int i = 0; i < 4; ++i){
    int idx = base + t + i * 256;
    if (idx < NN) v += deg[idx];
  }
  s[t] = v; __syncthreads();
  for (int o = 128; o; o >>= 1){
    if (t < o) s[t] += s[t + o];
    __syncthreads();
  }
  if (t == 0) bsum[b] = s[0];
}

__global__ void k_scan2(const int* __restrict__ bsum, int* __restrict__ boff){
  __shared__ int s[128];
  int t = threadIdx.x;
  int v = (t < NB_SCAN) ? bsum[t] : 0;
  s[t] = v; __syncthreads();
  for (int o = 1; o < 128; o <<= 1){
    int x = (t >= o) ? s[t - o] : 0;
    __syncthreads();
    s[t] += x;
    __syncthreads();
  }
  if (t < NB_SCAN) boff[t] = s[t] - v;  // exclusive block offsets
}

__global__ void k_scan3(const int* __restrict__ deg, const int* __restrict__ boff,
                        int* __restrict__ rowptr, int* __restrict__ cursor){
  __shared__ int s[256];
  int b = blockIdx.x, t = threadIdx.x;
  int base = b * 1024 + t * 4;
  int d[4]; int loc = 0;
  #pragma unroll
  for (int i = 0; i < 4; ++i){
    int idx = base + i;
    d[i] = (idx < NN) ? deg[idx] : 0;
    loc += d[i];
  }
  s[t] = loc; __syncthreads();
  for (int o = 1; o < 256; o <<= 1){
    int x = (t >= o) ? s[t - o] : 0;
    __syncthreads();
    s[t] += x;
    __syncthreads();
  }
  int run = boff[b] + s[t] - loc;
  #pragma unroll
  for (int i = 0; i < 4; ++i){
    int idx = base + i;
    if (idx < NN){ rowptr[idx] = run; cursor[idx] = run; run += d[i]; }
  }
  if (b == NB_SCAN - 1 && t == 255) rowptr[NN] = run;  // = NE
}

// CSR fill: bucket edges by dst; store src index and weight dinv[src]
__global__ void k_fill(const int* __restrict__ src, const int* __restrict__ dst,
                       const float* __restrict__ dinv, int* __restrict__ cursor,
                       int* __restrict__ csr_src, float* __restrict__ csr_w){
  int e = blockIdx.x * blockDim.x + threadIdx.x;
  if (e >= NE) return;
  int s = src[e], d = dst[e];
  int p = atomicAdd(&cursor[d], 1);
  csr_src[p] = s;
  csr_w[p] = dinv[s];
}

// graph boundaries from sorted batch ids; start[NG] = NN
__global__ void k_bounds(const int* __restrict__ batch, int* __restrict__ start){
  int i = blockIdx.x * blockDim.x + threadIdx.x;
  if (i >= NN) return;
  int cur = batch[i];
  int prev = (i == 0) ? -1 : batch[i - 1];
  for (int g = prev + 1; g <= cur; ++g) start[g] = i;
  if (i == NN - 1) for (int g = cur + 1; g <= NG; ++g) start[g] = NN;
}

// Repack W[K,256] f32 -> bf16 MFMA B-operand order
__global__ void k_repack(const float* __restrict__ W,
                         unsigned short* __restrict__ Wp, int K){
  int gid = blockIdx.x * blockDim.x + threadIdx.x;
  int total = (K >> 5) * 16 * 64;
  if (gid >= total) return;
  int l = gid & 63;
  int t = (gid >> 6) & 15;
  int kb = gid >> 10;
  int q = l >> 4, m = l & 15;
  unsigned short* o = Wp + (size_t)gid * 8;
  #pragma unroll
  for (int j = 0; j < 8; ++j)
    o[j] = f2bf(W[(size_t)(kb * 32 + q * 8 + j) * 256 + t * 16 + m]);
}

// Layer 0: B(bf16) = x(f32)[N,128] @ Wp. Split hi/lo bf16, no BN fold needed.
__global__ __launch_bounds__(256) void k_gemm0(const float* __restrict__ A,
                                               const unsigned short* __restrict__ Wp,
                                               unsigned short* __restrict__ out){
  const int K = 128;
  int lane = threadIdx.x & 63;
  int wave = threadIdx.x >> 6;
  int m0 = blockIdx.x * 64 + wave * 16;
  int q = lane >> 4, m = lane & 15;
  int arow = m0 + m;
  bool valid = arow < NN;
  const float* ap = A + (size_t)arow * K + q * 8;
  f32x4 acc[16] = {};
  for (int kb = 0; kb < 4; ++kb){
    short8 ahi = {}, alo = {};
    if (valid){
      f32x4 x0 = *(const f32x4*)(ap + kb * 32);
      f32x4 x1 = *(const f32x4*)(ap + kb * 32 + 4);
      float xs[8] = {x0[0], x0[1], x0[2], x0[3], x1[0], x1[1], x1[2], x1[3]};
      #pragma unroll
      for (int j = 0; j < 8; ++j){
        unsigned short h = f2bf(xs[j]);
        ahi[j] = (short)h;
        alo[j] = (short)f2bf(xs[j] - bf2f(h));
      }
    }
    const unsigned short* wp = Wp + ((size_t)kb * 1024 + lane) * 8;
    #pragma unroll
    for (int t = 0; t < 16; ++t){
      short8 b = *(const short8*)(wp + (size_t)t * 512);
      acc[t] = __builtin_amdgcn_mfma_f32_16x16x32_bf16(ahi, b, acc[t], 0, 0, 0);
      acc[t] = __builtin_amdgcn_mfma_f32_16x16x32_bf16(alo, b, acc[t], 0, 0, 0);
    }
  }
  int r0 = m0 + q * 4;
  #pragma unroll
  for (int t = 0; t < 16; ++t)
    #pragma unroll
    for (int r = 0; r < 4; ++r){
      int row = r0 + r;
      if (row < NN) out[(size_t)row * 256 + t * 16 + m] = f2bf(acc[t][r]);
    }
}

// Layers 1-2: B(bf16) = (cA[k]*C(bf16)[N,256]+cB[k]) @ Wp. Affine in f32, split hi/lo.
__global__ __launch_bounds__(256) void k_gemm12(const unsigned short* __restrict__ A,
                                                const unsigned short* __restrict__ Wp,
                                                const float* __restrict__ cA,
                                                const float* __restrict__ cB,
                                                unsigned short* __restrict__ out){
  const int K = 256;
  __shared__ float sA[256], sB[256];
  sA[threadIdx.x] = cA[threadIdx.x];
  sB[threadIdx.x] = cB[threadIdx.x];
  __syncthreads();
  int lane = threadIdx.x & 63;
  int wave = threadIdx.x >> 6;
  int m0 = blockIdx.x * 64 + wave * 16;
  int q = lane >> 4, m = lane & 15;
  int arow = m0 + m;
  bool valid = arow < NN;
  const unsigned short* ap = A + (size_t)arow * K + q * 8;
  f32x4 acc[16] = {};
  for (int kb = 0; kb < 8; ++kb){
    short8 ahi = {}, alo = {};
    if (valid){
      u16x8 av = *(const u16x8*)(ap + kb * 32);
      int kk = kb * 32 + q * 8;
      #pragma unroll
      for (int j = 0; j < 8; ++j){
        float xv = sA[kk + j] * bf2f(av[j]) + sB[kk + j];
        unsigned short h = f2bf(xv);
        ahi[j] = (short)h;
        alo[j] = (short)f2bf(xv - bf2f(h));
      }
    }
    const unsigned short* wp = Wp + ((size_t)kb * 1024 + lane) * 8;
    #pragma unroll
    for (int t = 0; t < 16; ++t){
      short8 b = *(const short8*)(wp + (size_t)t * 512);
      acc[t] = __builtin_amdgcn_mfma_f32_16x16x32_bf16(ahi, b, acc[t], 0, 0, 0);
      acc[t] = __builtin_amdgcn_mfma_f32_16x16x32_bf16(alo, b, acc[t], 0, 0, 0);
    }
  }
  int r0 = m0 + q * 4;
  #pragma unroll
  for (int t = 0; t < 16; ++t)
    #pragma unroll
    for (int r = 0; r < 4; ++r){
      int row = r0 + r;
      if (row < NN) out[(size_t)row * 256 + t * 16 + m] = f2bf(acc[t][r]);
    }
}

// Pull aggregation + bias + tanh + BN-stats, fused; B bf16 in, C bf16 out.
// grid = 512 blocks (measured optimum); depth-2 pipelined edge loop for MLP.
__global__ __launch_bounds__(256) void k_gather(const int* __restrict__ rowptr,
                                                const int* __restrict__ csr_src,
                                                const float* __restrict__ csr_w,
                                                const float* __restrict__ dinv,
                                                const unsigned short* __restrict__ B,
                                                const float* __restrict__ bias,
                                                unsigned short* __restrict__ C,
                                                float* __restrict__ gsum,
                                                float* __restrict__ gsumsq){
  __shared__ float lsum[4][256];
  __shared__ float lss[4][256];
  int lane = threadIdx.x & 63;
  int wv = threadIdx.x >> 6;
  int gwv = (int)((blockIdx.x * 256 + threadIdx.x) >> 6);
  int nwv = (int)((gridDim.x * 256) >> 6);
  int c4 = lane * 4;
  f32x4 bia = *(const f32x4*)(bias + c4);
  f32x4 s = {}, ss = {};
  for (int v = gwv; v < NN; v += nwv){
    float dv = dinv[v];
    u16x4 bv = *(const u16x4*)(B + (size_t)v * 256 + c4);
    f32x4 acc;
    acc[0] = dv * bf2f(bv[0]);
    acc[1] = dv * bf2f(bv[1]);
    acc[2] = dv * bf2f(bv[2]);
    acc[3] = dv * bf2f(bv[3]);
    int e = rowptr[v], e1 = rowptr[v + 1];
    if (e < e1){
      // depth-2 pipeline: row-load for e+1 issued before consuming row e
      int sv = csr_src[e];
      float wc = csr_w[e];
      u16x4 rv = *(const u16x4*)(B + (size_t)sv * 256 + c4);
      for (++e; e < e1; ++e){
        int svn = csr_src[e];
        float wn = csr_w[e];
        u16x4 rn = *(const u16x4*)(B + (size_t)svn * 256 + c4);
        acc[0] += wc * bf2f(rv[0]);
        acc[1] += wc * bf2f(rv[1]);
        acc[2] += wc * bf2f(rv[2]);
        acc[3] += wc * bf2f(rv[3]);
        rv = rn; wc = wn;
      }
      acc[0] += wc * bf2f(rv[0]);
      acc[1] += wc * bf2f(rv[1]);
      acc[2] += wc * bf2f(rv[2]);
      acc[3] += wc * bf2f(rv[3]);
    }
    f32x4 t;
    t[0] = tanhf(dv * acc[0] + bia[0]);
    t[1] = tanhf(dv * acc[1] + bia[1]);
    t[2] = tanhf(dv * acc[2] + bia[2]);
    t[3] = tanhf(dv * acc[3] + bia[3]);
    u16x4 ct;
    ct[0] = f2bf(t[0]); ct[1] = f2bf(t[1]); ct[2] = f2bf(t[2]); ct[3] = f2bf(t[3]);
    *(u16x4*)(C + (size_t)v * 256 + c4) = ct;
    s += t;
    ss += t * t;
  }
  *(f32x4*)(&lsum[wv][c4]) = s;
  *(f32x4*)(&lss[wv][c4]) = ss;
  __syncthreads();
  if (wv == 0){
    f32x4 a = *(f32x4*)(&lsum[0][c4]);
    f32x4 b = *(f32x4*)(&lss[0][c4]);
    #pragma unroll
    for (int w2 = 1; w2 < 4; ++w2){
      a += *(f32x4*)(&lsum[w2][c4]);
      b += *(f32x4*)(&lss[w2][c4]);
    }
    #pragma unroll
    for (int i = 0; i < 4; ++i){
      atomicAdd(&gsum[c4 + i], a[i]);
      atomicAdd(&gsumsq[c4 + i], b[i]);
    }
  }
}

__global__ void k_bncoef(const float* __restrict__ gsum, const float* __restrict__ gsumsq,
                         const float* __restrict__ gamma,
                         const float* __restrict__ beta,
                         float* __restrict__ coefA, float* __restrict__ coefB){
  int c = threadIdx.x;
  float mu = gsum[c] * (1.f / NN);
  float var = gsumsq[c] * (1.f / NN) - mu * mu;
  float a = gamma[c] / sqrtf(var + BN_EPS);
  coefA[c] = a;
  coefB[c] = beta[c] - mu * a;
}

// block per graph; thread c: max&min over pre-BN bf16 C, then apply affine
__global__ void k_pool(const unsigned short* __restrict__ C, const int* __restrict__ start,
                       const float* __restrict__ coefA, const float* __restrict__ coefB,
                       float* __restrict__ out){
  int g = blockIdx.x, c = threadIdx.x;
  int s = start[g], e = start[g + 1];
  float mx = -INFINITY, mn = INFINITY;
  for (int row = s; row < e; ++row){
    float v = bf2f(C[(size_t)row * 256 + c]);
    mx = fmaxf(mx, v);
    mn = fminf(mn, v);
  }
  float a = coefA[c], b = coefB[c];
  float r = (a >= 0.f) ? (a * mx + b) : (a * mn + b);
  out[(size_t)g * 256 + c] = (e > s) ? r : 0.f;
}

extern "C" void kernel_launch(void* const* d_in, const int* in_sizes, int n_in,
                              void* d_out, int out_size, void* d_ws, size_t ws_size,
                              hipStream_t stream){
  const float* x = (const float*)d_in[0];
  const int* eidx = (const int*)d_in[1];
  const int* batch = (const int*)d_in[2];
  const int* src  = eidx;
  const int* dstv = eidx + NE;
  const float* W[3]  = {(const float*)d_in[3],  (const float*)d_in[7],  (const float*)d_in[11]};
  const float* bb[3] = {(const float*)d_in[4],  (const float*)d_in[8],  (const float*)d_in[12]};
  const float* gm[3] = {(const float*)d_in[5],  (const float*)d_in[9],  (const float*)d_in[13]};
  const float* bt[3] = {(const float*)d_in[6],  (const float*)d_in[10], (const float*)d_in[14]};
  float* out = (float*)d_out;

  char* w = (char*)d_ws;
  unsigned short* B = (unsigned short*)w; w += (size_t)NN * 256 * 2;  // 51.2 MB bf16
  unsigned short* C = (unsigned short*)w; w += (size_t)NN * 256 * 2;  // 51.2 MB bf16
  float* dinv = (float*)w;         w += (size_t)NN * 4;
  int* deg = (int*)w;              w += (size_t)NN * 4;
  int* rowptr = (int*)w;           w += (size_t)(NN + 1) * 4;
  int* cursor = (int*)w;           w += (size_t)NN * 4;
  int* csr_src = (int*)w;          w += (size_t)NE * 4;
  float* csr_w = (float*)w;        w += (size_t)NE * 4;
  int* bsum = (int*)w;             w += (size_t)NB_SCAN * 4;
  int* boff = (int*)w;             w += (size_t)NB_SCAN * 4;
  unsigned short* Wp = (unsigned short*)w; w += (size_t)256 * 256 * 2;
  float* gsum = (float*)w;         w += 256 * 4;
  float* gsumsq = (float*)w;       w += 256 * 4;
  float* coefA = (float*)w;        w += 256 * 4;
  float* coefB = (float*)w;        w += 256 * 4;
  int* start = (int*)w;            w += (size_t)(NG + 1) * 4;

  // graph prep (once per call)
  k_zero<<<(NN + 255) / 256, 256, 0, stream>>>((float*)deg, NN);
  k_deg<<<(NE + 255) / 256, 256, 0, stream>>>(dstv, deg);
  k_dinv<<<(NN + 255) / 256, 256, 0, stream>>>(deg, dinv);
  k_scan1<<<NB_SCAN, 256, 0, stream>>>(deg, bsum);
  k_scan2<<<1, 128, 0, stream>>>(bsum, boff);
  k_scan3<<<NB_SCAN, 256, 0, stream>>>(deg, boff, rowptr, cursor);
  k_fill<<<(NE + 255) / 256, 256, 0, stream>>>(src, dstv, dinv, cursor, csr_src, csr_w);
  k_bounds<<<(NN + 255) / 256, 256, 0, stream>>>(batch, start);

  for (int L = 0; L < 3; ++L){
    int K = (L == 0) ? 128 : 256;
    int nrep = (K >> 5) * 16 * 64;
    k_repack<<<(nrep + 255) / 256, 256, 0, stream>>>(W[L], Wp, K);
    if (L == 0) k_gemm0<<<(NN + 63) / 64, 256, 0, stream>>>(x, Wp, B);
    else        k_gemm12<<<(NN + 63) / 64, 256, 0, stream>>>(C, Wp, coefA, coefB, B);
    k_zero<<<2, 256, 0, stream>>>(gsum, 512);  // gsum+gsumsq contiguous
    k_gather<<<512, 256, 0, stream>>>(rowptr, csr_src, csr_w, dinv, B, bb[L], C, gsum, gsumsq);
    k_bncoef<<<1, 256, 0, stream>>>(gsum, gsumsq, gm[L], bt[L], coefA, coefB);
    k_pool<<<NG, 256, 0, stream>>>(C, start, coefA, coefB, out + (size_t)L * NG * 256);
  }
}

// Round 12
// 1031.986 us; speedup vs baseline: 1.4473x; 1.0341x over previous
//
#include <hip/hip_runtime.h>
#include <hip/hip_bf16.h>
#include <math.h>

#define NN 100000
#define NE 400000
#define NG 2048
#define BN_EPS 1e-5f
#define NB_SCAN 98   // ceil(NN/1024)

typedef short short8 __attribute__((ext_vector_type(8)));
typedef float f32x4 __attribute__((ext_vector_type(4)));
typedef unsigned short u16x4 __attribute__((ext_vector_type(4)));
typedef unsigned short u16x8 __attribute__((ext_vector_type(8)));

__device__ __forceinline__ float bf2f(unsigned short u){
  union { unsigned u; float f; } x; x.u = ((unsigned)u) << 16; return x.f;
}
__device__ __forceinline__ unsigned short f2bf(float f){
  union { float f; unsigned u; } x; x.f = f;
  unsigned r = x.u + 0x7FFFu + ((x.u >> 16) & 1u);
  return (unsigned short)(r >> 16);
}

__global__ void k_zero(float* p, long n){
  long i = (long)blockIdx.x * blockDim.x + threadIdx.x;
  if (i < n) p[i] = 0.f;
}

__global__ void k_deg(const int* __restrict__ dst, int* __restrict__ deg){
  int e = blockIdx.x * blockDim.x + threadIdx.x;
  if (e < NE) atomicAdd(&deg[dst[e]], 1);
}

__global__ void k_dinv(const int* __restrict__ deg, float* __restrict__ dinv){
  int v = blockIdx.x * blockDim.x + threadIdx.x;
  if (v < NN) dinv[v] = rsqrtf((float)(deg[v] + 1));  // +1 = self loop
}

// ---- parallel exclusive scan of deg -> rowptr/cursor (3 phases) ----
__global__ void k_scan1(const int* __restrict__ deg, int* __restrict__ bsum){
  __shared__ int s[256];
  int b = blockIdx.x, t = threadIdx.x;
  int base = b * 1024;
  int v = 0;
  #pragma unroll
  for (int i = 0; i < 4; ++i){
    int idx = base + t + i * 256;
    if (idx < NN) v += deg[idx];
  }
  s[t] = v; __syncthreads();
  for (int o = 128; o; o >>= 1){
    if (t < o) s[t] += s[t + o];
    __syncthreads();
  }
  if (t == 0) bsum[b] = s[0];
}

__global__ void k_scan2(const int* __restrict__ bsum, int* __restrict__ boff){
  __shared__ int s[128];
  int t = threadIdx.x;
  int v = (t < NB_SCAN) ? bsum[t] : 0;
  s[t] = v; __syncthreads();
  for (int o = 1; o < 128; o <<= 1){
    int x = (t >= o) ? s[t - o] : 0;
    __syncthreads();
    s[t] += x;
    __syncthreads();
  }
  if (t < NB_SCAN) boff[t] = s[t] - v;  // exclusive block offsets
}

__global__ void k_scan3(const int* __restrict__ deg, const int* __restrict__ boff,
                        int* __restrict__ rowptr, int* __restrict__ cursor){
  __shared__ int s[256];
  int b = blockIdx.x, t = threadIdx.x;
  int base = b * 1024 + t * 4;
  int d[4]; int loc = 0;
  #pragma unroll
  for (int i = 0; i < 4; ++i){
    int idx = base + i;
    d[i] = (idx < NN) ? deg[idx] : 0;
    loc += d[i];
  }
  s[t] = loc; __syncthreads();
  for (int o = 1; o < 256; o <<= 1){
    int x = (t >= o) ? s[t - o] : 0;
    __syncthreads();
    s[t] += x;
    __syncthreads();
  }
  int run = boff[b] + s[t] - loc;
  #pragma unroll
  for (int i = 0; i < 4; ++i){
    int idx = base + i;
    if (idx < NN){ rowptr[idx] = run; cursor[idx] = run; run += d[i]; }
  }
  if (b == NB_SCAN - 1 && t == 255) rowptr[NN] = run;  // = NE
}

// CSR fill: bucket edges by dst; store src index and weight dinv[src]
__global__ void k_fill(const int* __restrict__ src, const int* __restrict__ dst,
                       const float* __restrict__ dinv, int* __restrict__ cursor,
                       int* __restrict__ csr_src, float* __restrict__ csr_w){
  int e = blockIdx.x * blockDim.x + threadIdx.x;
  if (e >= NE) return;
  int s = src[e], d = dst[e];
  int p = atomicAdd(&cursor[d], 1);
  csr_src[p] = s;
  csr_w[p] = dinv[s];
}

// graph boundaries from sorted batch ids; start[NG] = NN
__global__ void k_bounds(const int* __restrict__ batch, int* __restrict__ start){
  int i = blockIdx.x * blockDim.x + threadIdx.x;
  if (i >= NN) return;
  int cur = batch[i];
  int prev = (i == 0) ? -1 : batch[i - 1];
  for (int g = prev + 1; g <= cur; ++g) start[g] = i;
  if (i == NN - 1) for (int g = cur + 1; g <= NG; ++g) start[g] = NN;
}

// Repack W[K,256] f32 -> bf16 MFMA B-operand order
__global__ void k_repack(const float* __restrict__ W,
                         unsigned short* __restrict__ Wp, int K){
  int gid = blockIdx.x * blockDim.x + threadIdx.x;
  int total = (K >> 5) * 16 * 64;
  if (gid >= total) return;
  int l = gid & 63;
  int t = (gid >> 6) & 15;
  int kb = gid >> 10;
  int q = l >> 4, m = l & 15;
  unsigned short* o = Wp + (size_t)gid * 8;
  #pragma unroll
  for (int j = 0; j < 8; ++j)
    o[j] = f2bf(W[(size_t)(kb * 32 + q * 8 + j) * 256 + t * 16 + m]);
}

// Layer 0: B(bf16) = x(f32)[N,128] @ Wp. Split hi/lo bf16.
__global__ __launch_bounds__(256) void k_gemm0(const float* __restrict__ A,
                                               const unsigned short* __restrict__ Wp,
                                               unsigned short* __restrict__ out){
  const int K = 128;
  int lane = threadIdx.x & 63;
  int wave = threadIdx.x >> 6;
  int m0 = blockIdx.x * 64 + wave * 16;
  int q = lane >> 4, m = lane & 15;
  int arow = m0 + m;
  bool valid = arow < NN;
  const float* ap = A + (size_t)arow * K + q * 8;
  f32x4 acc[16] = {};
  for (int kb = 0; kb < 4; ++kb){
    short8 ahi = {}, alo = {};
    if (valid){
      f32x4 x0 = *(const f32x4*)(ap + kb * 32);
      f32x4 x1 = *(const f32x4*)(ap + kb * 32 + 4);
      float xs[8] = {x0[0], x0[1], x0[2], x0[3], x1[0], x1[1], x1[2], x1[3]};
      #pragma unroll
      for (int j = 0; j < 8; ++j){
        unsigned short h = f2bf(xs[j]);
        ahi[j] = (short)h;
        alo[j] = (short)f2bf(xs[j] - bf2f(h));
      }
    }
    const unsigned short* wp = Wp + ((size_t)kb * 1024 + lane) * 8;
    #pragma unroll
    for (int t = 0; t < 16; ++t){
      short8 b = *(const short8*)(wp + (size_t)t * 512);
      acc[t] = __builtin_amdgcn_mfma_f32_16x16x32_bf16(ahi, b, acc[t], 0, 0, 0);
      acc[t] = __builtin_amdgcn_mfma_f32_16x16x32_bf16(alo, b, acc[t], 0, 0, 0);
    }
  }
  int r0 = m0 + q * 4;
  #pragma unroll
  for (int t = 0; t < 16; ++t)
    #pragma unroll
    for (int r = 0; r < 4; ++r){
      int row = r0 + r;
      if (row < NN) out[(size_t)row * 256 + t * 16 + m] = f2bf(acc[t][r]);
    }
}

// Layers 1-2: B(bf16) = (cA[k]*C(bf16)[N,256]+cB[k]) @ Wp.
__global__ __launch_bounds__(256) void k_gemm12(const unsigned short* __restrict__ A,
                                                const unsigned short* __restrict__ Wp,
                                                const float* __restrict__ cA,
                                                const float* __restrict__ cB,
                                                unsigned short* __restrict__ out){
  const int K = 256;
  __shared__ float sA[256], sB[256];
  sA[threadIdx.x] = cA[threadIdx.x];
  sB[threadIdx.x] = cB[threadIdx.x];
  __syncthreads();
  int lane = threadIdx.x & 63;
  int wave = threadIdx.x >> 6;
  int m0 = blockIdx.x * 64 + wave * 16;
  int q = lane >> 4, m = lane & 15;
  int arow = m0 + m;
  bool valid = arow < NN;
  const unsigned short* ap = A + (size_t)arow * K + q * 8;
  f32x4 acc[16] = {};
  for (int kb = 0; kb < 8; ++kb){
    short8 ahi = {}, alo = {};
    if (valid){
      u16x8 av = *(const u16x8*)(ap + kb * 32);
      int kk = kb * 32 + q * 8;
      #pragma unroll
      for (int j = 0; j < 8; ++j){
        float xv = sA[kk + j] * bf2f(av[j]) + sB[kk + j];
        unsigned short h = f2bf(xv);
        ahi[j] = (short)h;
        alo[j] = (short)f2bf(xv - bf2f(h));
      }
    }
    const unsigned short* wp = Wp + ((size_t)kb * 1024 + lane) * 8;
    #pragma unroll
    for (int t = 0; t < 16; ++t){
      short8 b = *(const short8*)(wp + (size_t)t * 512);
      acc[t] = __builtin_amdgcn_mfma_f32_16x16x32_bf16(ahi, b, acc[t], 0, 0, 0);
      acc[t] = __builtin_amdgcn_mfma_f32_16x16x32_bf16(alo, b, acc[t], 0, 0, 0);
    }
  }
  int r0 = m0 + q * 4;
  #pragma unroll
  for (int t = 0; t < 16; ++t)
    #pragma unroll
    for (int r = 0; r < 4; ++r){
      int row = r0 + r;
      if (row < NN) out[(size_t)row * 256 + t * 16 + m] = f2bf(acc[t][r]);
    }
}

// Pull aggregation + bias + tanh + BN-stats. B bf16 in, C bf16 out.
// grid = 512 (measured optimum). Dual-stream edge loop + depth-2 pipeline:
// 2 independent accumulators, up to 4 row-loads in flight per wave.
__global__ __launch_bounds__(256) void k_gather(const int* __restrict__ rowptr,
                                                const int* __restrict__ csr_src,
                                                const float* __restrict__ csr_w,
                                                const float* __restrict__ dinv,
                                                const unsigned short* __restrict__ B,
                                                const float* __restrict__ bias,
                                                unsigned short* __restrict__ C,
                                                float* __restrict__ gsum,
                                                float* __restrict__ gsumsq){
  __shared__ float lsum[4][256];
  __shared__ float lss[4][256];
  int lane = threadIdx.x & 63;
  int wv = threadIdx.x >> 6;
  int gwv = (int)((blockIdx.x * 256 + threadIdx.x) >> 6);
  int nwv = (int)((gridDim.x * 256) >> 6);
  int c4 = lane * 4;
  f32x4 bia = *(const f32x4*)(bias + c4);
  f32x4 s = {}, ss = {};
  for (int v = gwv; v < NN; v += nwv){
    float dv = dinv[v];
    u16x4 bv = *(const u16x4*)(B + (size_t)v * 256 + c4);
    f32x4 acc, acc2 = {};
    acc[0] = dv * bf2f(bv[0]);
    acc[1] = dv * bf2f(bv[1]);
    acc[2] = dv * bf2f(bv[2]);
    acc[3] = dv * bf2f(bv[3]);
    int e = rowptr[v], e1 = rowptr[v + 1];
    if (e1 - e >= 2){
      int sa = csr_src[e],   sb = csr_src[e + 1];
      float wa = csr_w[e],   wb = csr_w[e + 1];
      u16x4 ra = *(const u16x4*)(B + (size_t)sa * 256 + c4);
      u16x4 rb = *(const u16x4*)(B + (size_t)sb * 256 + c4);
      e += 2;
      while (e + 1 < e1){
        int sc = csr_src[e],   sd = csr_src[e + 1];
        float wc = csr_w[e],   wd = csr_w[e + 1];
        u16x4 rc = *(const u16x4*)(B + (size_t)sc * 256 + c4);
        u16x4 rd = *(const u16x4*)(B + (size_t)sd * 256 + c4);
        acc[0]  += wa * bf2f(ra[0]); acc[1]  += wa * bf2f(ra[1]);
        acc[2]  += wa * bf2f(ra[2]); acc[3]  += wa * bf2f(ra[3]);
        acc2[0] += wb * bf2f(rb[0]); acc2[1] += wb * bf2f(rb[1]);
        acc2[2] += wb * bf2f(rb[2]); acc2[3] += wb * bf2f(rb[3]);
        ra = rc; rb = rd; wa = wc; wb = wd;
        e += 2;
      }
      acc[0]  += wa * bf2f(ra[0]); acc[1]  += wa * bf2f(ra[1]);
      acc[2]  += wa * bf2f(ra[2]); acc[3]  += wa * bf2f(ra[3]);
      acc2[0] += wb * bf2f(rb[0]); acc2[1] += wb * bf2f(rb[1]);
      acc2[2] += wb * bf2f(rb[2]); acc2[3] += wb * bf2f(rb[3]);
    }
    if (e < e1){
      int sv = csr_src[e];
      float wc = csr_w[e];
      u16x4 rv = *(const u16x4*)(B + (size_t)sv * 256 + c4);
      acc[0] += wc * bf2f(rv[0]); acc[1] += wc * bf2f(rv[1]);
      acc[2] += wc * bf2f(rv[2]); acc[3] += wc * bf2f(rv[3]);
    }
    acc += acc2;
    f32x4 t;
    t[0] = tanhf(dv * acc[0] + bia[0]);
    t[1] = tanhf(dv * acc[1] + bia[1]);
    t[2] = tanhf(dv * acc[2] + bia[2]);
    t[3] = tanhf(dv * acc[3] + bia[3]);
    u16x4 ct;
    ct[0] = f2bf(t[0]); ct[1] = f2bf(t[1]); ct[2] = f2bf(t[2]); ct[3] = f2bf(t[3]);
    *(u16x4*)(C + (size_t)v * 256 + c4) = ct;
    s += t;
    ss += t * t;
  }
  *(f32x4*)(&lsum[wv][c4]) = s;
  *(f32x4*)(&lss[wv][c4]) = ss;
  __syncthreads();
  if (wv == 0){
    f32x4 a = *(f32x4*)(&lsum[0][c4]);
    f32x4 b = *(f32x4*)(&lss[0][c4]);
    #pragma unroll
    for (int w2 = 1; w2 < 4; ++w2){
      a += *(f32x4*)(&lsum[w2][c4]);
      b += *(f32x4*)(&lss[w2][c4]);
    }
    #pragma unroll
    for (int i = 0; i < 4; ++i){
      atomicAdd(&gsum[c4 + i], a[i]);
      atomicAdd(&gsumsq[c4 + i], b[i]);
    }
  }
}

__global__ void k_bncoef(const float* __restrict__ gsum, const float* __restrict__ gsumsq,
                         const float* __restrict__ gamma,
                         const float* __restrict__ beta,
                         float* __restrict__ coefA, float* __restrict__ coefB){
  int c = threadIdx.x;
  float mu = gsum[c] * (1.f / NN);
  float var = gsumsq[c] * (1.f / NN) - mu * mu;
  float a = gamma[c] / sqrtf(var + BN_EPS);
  coefA[c] = a;
  coefB[c] = beta[c] - mu * a;
}

// block per graph; thread c: max&min over pre-BN bf16 C, then apply affine
__global__ void k_pool(const unsigned short* __restrict__ C, const int* __restrict__ start,
                       const float* __restrict__ coefA, const float* __restrict__ coefB,
                       float* __restrict__ out){
  int g = blockIdx.x, c = threadIdx.x;
  int s = start[g], e = start[g + 1];
  float mx = -INFINITY, mn = INFINITY;
  for (int row = s; row < e; ++row){
    float v = bf2f(C[(size_t)row * 256 + c]);
    mx = fmaxf(mx, v);
    mn = fminf(mn, v);
  }
  float a = coefA[c], b = coefB[c];
  float r = (a >= 0.f) ? (a * mx + b) : (a * mn + b);
  out[(size_t)g * 256 + c] = (e > s) ? r : 0.f;
}

extern "C" void kernel_launch(void* const* d_in, const int* in_sizes, int n_in,
                              void* d_out, int out_size, void* d_ws, size_t ws_size,
                              hipStream_t stream){
  const float* x = (const float*)d_in[0];
  const int* eidx = (const int*)d_in[1];
  const int* batch = (const int*)d_in[2];
  const int* src  = eidx;
  const int* dstv = eidx + NE;
  const float* W[3]  = {(const float*)d_in[3],  (const float*)d_in[7],  (const float*)d_in[11]};
  const float* bb[3] = {(const float*)d_in[4],  (const float*)d_in[8],  (const float*)d_in[12]};
  const float* gm[3] = {(const float*)d_in[5],  (const float*)d_in[9],  (const float*)d_in[13]};
  const float* bt[3] = {(const float*)d_in[6],  (const float*)d_in[10], (const float*)d_in[14]};
  float* out = (float*)d_out;

  char* w = (char*)d_ws;
  unsigned short* B = (unsigned short*)w; w += (size_t)NN * 256 * 2;  // 51.2 MB bf16
  unsigned short* C = (unsigned short*)w; w += (size_t)NN * 256 * 2;  // 51.2 MB bf16
  float* dinv = (float*)w;         w += (size_t)NN * 4;
  int* deg = (int*)w;              w += (size_t)NN * 4;
  int* rowptr = (int*)w;           w += (size_t)(NN + 1) * 4;
  int* cursor = (int*)w;           w += (size_t)NN * 4;
  int* csr_src = (int*)w;          w += (size_t)NE * 4;
  float* csr_w = (float*)w;        w += (size_t)NE * 4;
  int* bsum = (int*)w;             w += (size_t)NB_SCAN * 4;
  int* boff = (int*)w;             w += (size_t)NB_SCAN * 4;
  unsigned short* Wp = (unsigned short*)w; w += (size_t)256 * 256 * 2;
  float* gsum = (float*)w;         w += 256 * 4;
  float* gsumsq = (float*)w;       w += 256 * 4;
  float* coefA = (float*)w;        w += 256 * 4;
  float* coefB = (float*)w;        w += 256 * 4;
  int* start = (int*)w;            w += (size_t)(NG + 1) * 4;

  // graph prep (once per call)
  k_zero<<<(NN + 255) / 256, 256, 0, stream>>>((float*)deg, NN);
  k_deg<<<(NE + 255) / 256, 256, 0, stream>>>(dstv, deg);
  k_dinv<<<(NN + 255) / 256, 256, 0, stream>>>(deg, dinv);
  k_scan1<<<NB_SCAN, 256, 0, stream>>>(deg, bsum);
  k_scan2<<<1, 128, 0, stream>>>(bsum, boff);
  k_scan3<<<NB_SCAN, 256, 0, stream>>>(deg, boff, rowptr, cursor);
  k_fill<<<(NE + 255) / 256, 256, 0, stream>>>(src, dstv, dinv, cursor, csr_src, csr_w);
  k_bounds<<<(NN + 255) / 256, 256, 0, stream>>>(batch, start);

  for (int L = 0; L < 3; ++L){
    int K = (L == 0) ? 128 : 256;
    int nrep = (K >> 5) * 16 * 64;
    k_repack<<<(nrep + 255) / 256, 256, 0, stream>>>(W[L], Wp, K);
    if (L == 0) k_gemm0<<<(NN + 63) / 64, 256, 0, stream>>>(x, Wp, B);
    else        k_gemm12<<<(NN + 63) / 64, 256, 0, stream>>>(C, Wp, coefA, coefB, B);
    k_zero<<<2, 256, 0, stream>>>(gsum, 512);  // gsum+gsumsq contiguous
    k_gather<<<512, 256, 0, stream>>>(rowptr, csr_src, csr_w, dinv, B, bb[L], C, gsum, gsumsq);
    k_bncoef<<<1, 256, 0, stream>>>(gsum, gsumsq, gm[L], bt[L], coefA, coefB);
    k_pool<<<NG, 256, 0, stream>>>(C, start, coefA, coefB, out + (size_t)L * NG * 256);
  }
}